// Round 1
// baseline (151.409 us; speedup 1.0000x reference)
//
#include <hip/hip_runtime.h>
#include <cstdint>
#include <cstddef>

// ---------------------------------------------------------------------------
// SelfAttention (b=4, C=64, 128x128) — MFMA bf16, round 5 (resubmit for
// baseline counters; previous bench attempt failed with GPU acquisition
// timeout, no profile captured).
// Math identical to rounds 2-4 (no-max softmax; pi-permuted Vpp/Wop so MFMA
// C-layout feeds the next MFMA B-operand by direct bitcast).
// Round-5:
//   k_qkv rewritten: x-tile staged in LDS (contiguous row-pair strips),
//     weights via wave-uniform broadcast reads, thread=(pooled cell, rowgroup)
//     so 2x2 maxpool is in-thread. Wo pack folded in (block 256).
//   k_lsum: Vpp pack fused into its epilogue (k_pack kernel removed).
//   k_attn: 512-thr blocks (8 waves, f split 8-ways) -> 32 waves/CU;
//     two-phase fp32 LDS reduction keeps LDS at 32 KB.
// ---------------------------------------------------------------------------

#define LOG2E 1.44269504088896340736f

typedef __attribute__((ext_vector_type(8)))  __bf16 bf8_t;
typedef __attribute__((ext_vector_type(16))) float  fx16;

__device__ __forceinline__ unsigned short f2bf(float f) {
  unsigned int u = __builtin_bit_cast(unsigned int, f);
  u += 0x7FFFu + ((u >> 16) & 1u);   // round-nearest-even
  return (unsigned short)(u >> 16);
}
__device__ __forceinline__ unsigned int pk2(unsigned short lo, unsigned short hi) {
  return (unsigned int)lo | ((unsigned int)hi << 16);
}
// involution permutation on a 16-group: swap middle two quads
__device__ __forceinline__ int pi16(int s) {
  int m = (s >> 2) & 3;
  return (m == 1 || m == 2) ? (s ^ 12) : s;
}
__device__ __forceinline__ float max4(const float* a) {
  return fmaxf(fmaxf(a[0], a[1]), fmaxf(a[2], a[3]));
}

#if __has_builtin(__builtin_amdgcn_exp2f)
#define EXP2F __builtin_amdgcn_exp2f
#else
#define EXP2F exp2f
#endif

// ----------------------- K1: fused q/k/v (one x pass) -----------------------
// grid 257: blocks 0..255 = (b, frow); block 256 packs Wo.
// Block: 4 waves; wave rg owns output rows 12rg..12rg+11; lane = pooled cell
// fc (64 cells of pooled row frow). Thread computes its 12 rows at the 4
// spatial positions of its cell (rows 2frow,2frow+1 x cols 2fc,2fc+1),
// pools k/v rows in-thread, writes q for all 4 positions.
__global__ void __launch_bounds__(256) k_qkv(const float* __restrict__ x,
                                             const float* __restrict__ Wq,
                                             const float* __restrict__ Wk,
                                             const float* __restrict__ Wv,
                                             const float* __restrict__ Wo,
                                             unsigned short* __restrict__ Qp,
                                             unsigned short* __restrict__ KpB,
                                             float* __restrict__ Vp,
                                             unsigned short* __restrict__ Wop) {
  if (blockIdx.x == 256) {                         // Wo -> bf16, pi on c-cols
    for (int i = threadIdx.x; i < 2048; i += 256) {
      int c = i & 31;
      Wop[i] = f2bf(Wo[(i & ~31) | (c & 16) | pi16(c & 15)]);
    }
    return;
  }
  __shared__ float ws[48][64];                     // [row][c]: q 0-7, k 8-15, v 16-47
  __shared__ float xs[16][256];                    // c-chunk x row-pair strip
  int t = threadIdx.x;
  for (int i = t; i < 512; i += 256) {
    ws[i >> 6][i & 63] = Wq[i];
    ws[8 + (i >> 6)][i & 63] = Wk[i];
  }
  for (int i = t; i < 2048; i += 256) ws[16 + (i >> 6)][i & 63] = Wv[i];
  int b = blockIdx.x >> 6, frow = blockIdx.x & 63;
  int rg = t >> 6, fc = t & 63;
  const float* xb = x + (size_t)b * (64 * 16384) + frow * 256;
  float acc[12][4];
#pragma unroll
  for (int j = 0; j < 12; ++j)
#pragma unroll
    for (int p = 0; p < 4; ++p) acc[j][p] = 0.f;
  int cl = t >> 4, seg = t & 15;                   // staging role
  for (int cc = 0; cc < 4; ++cc) {
    __syncthreads();                               // xs free (covers ws on cc=0)
    const float4* src =
        reinterpret_cast<const float4*>(xb + (size_t)(cc * 16 + cl) * 16384 + seg * 16);
    float4* dst = reinterpret_cast<float4*>(&xs[cl][seg * 16]);
#pragma unroll
    for (int j = 0; j < 4; ++j) dst[j] = src[j];
    __syncthreads();
#pragma unroll
    for (int c16 = 0; c16 < 16; ++c16) {
      int c = cc * 16 + c16;
      float2 xa = *reinterpret_cast<const float2*>(&xs[c16][2 * fc]);
      float2 xbv = *reinterpret_cast<const float2*>(&xs[c16][128 + 2 * fc]);
#pragma unroll
      for (int j = 0; j < 12; ++j) {
        float w = ws[12 * rg + j][c];              // wave-uniform -> broadcast
        acc[j][0] = fmaf(w, xa.x, acc[j][0]);
        acc[j][1] = fmaf(w, xa.y, acc[j][1]);
        acc[j][2] = fmaf(w, xbv.x, acc[j][2]);
        acc[j][3] = fmaf(w, xbv.y, acc[j][3]);
      }
    }
  }
  size_t idx = (size_t)b * 4096 + frow * 64 + fc;
  uint4 z4; z4.x = z4.y = z4.z = z4.w = 0u;
  if (rg == 0) {
    // q rows 0-7, per position
#pragma unroll
    for (int p = 0; p < 4; ++p) {
      int kpos = frow * 256 + (p >> 1) * 128 + 2 * fc + (p & 1);
      uint4 qa;
      qa.x = pk2(f2bf(acc[0][p]), f2bf(acc[1][p]));
      qa.y = pk2(f2bf(acc[2][p]), f2bf(acc[3][p]));
      qa.z = pk2(f2bf(acc[4][p]), f2bf(acc[5][p]));
      qa.w = pk2(f2bf(acc[6][p]), f2bf(acc[7][p]));
      uint4* qdst = reinterpret_cast<uint4*>(Qp + ((size_t)b * 16384 + kpos) * 16);
      qdst[0] = qa; qdst[1] = z4;
    }
    // k chans 0-3 (rows 8-11), pooled
    uint2 kw;
    kw.x = pk2(f2bf(max4(acc[8]) * LOG2E), f2bf(max4(acc[9]) * LOG2E));
    kw.y = pk2(f2bf(max4(acc[10]) * LOG2E), f2bf(max4(acc[11]) * LOG2E));
    *reinterpret_cast<uint2*>(KpB + idx * 16) = kw;
  } else if (rg == 1) {
    // k chans 4-7 (rows 12-15) + zero pad slots 8-15
    uint2 kw;
    kw.x = pk2(f2bf(max4(acc[0]) * LOG2E), f2bf(max4(acc[1]) * LOG2E));
    kw.y = pk2(f2bf(max4(acc[2]) * LOG2E), f2bf(max4(acc[3]) * LOG2E));
    *reinterpret_cast<uint2*>(KpB + idx * 16 + 4) = kw;
    *reinterpret_cast<uint4*>(KpB + idx * 16 + 8) = z4;
    // v chans 0-7 (rows 16-23), pooled
    float* vd = Vp + idx * 32;
    *reinterpret_cast<float4*>(vd) =
        make_float4(max4(acc[4]), max4(acc[5]), max4(acc[6]), max4(acc[7]));
    *reinterpret_cast<float4*>(vd + 4) =
        make_float4(max4(acc[8]), max4(acc[9]), max4(acc[10]), max4(acc[11]));
  } else {
    // rg2: v chans 8-19 (rows 24-35); rg3: v chans 20-31 (rows 36-47)
    float* vd = Vp + idx * 32 + (rg == 2 ? 8 : 20);
#pragma unroll
    for (int j4 = 0; j4 < 3; ++j4)
      *reinterpret_cast<float4*>(vd + 4 * j4) =
          make_float4(max4(acc[4 * j4]), max4(acc[4 * j4 + 1]),
                      max4(acc[4 * j4 + 2]), max4(acc[4 * j4 + 3]));
  }
}

// ----------------- K2: l = sum exp2(S2)  +  fused Vpp pack ------------------
// block = 1024 thr (16 waves) per (b, f-group pair of 64 rows); each wave
// owns a 1024-k slice; one Q fragment load feeds 2 MFMAs (FB=2).
// Epilogue: L -> Linv, then Vpp[b][c][f'] = bf16(Vp[b][pi(f)][c] * Linv).
__global__ void __launch_bounds__(1024) k_lsum(const unsigned short* __restrict__ Qp,
                                               const unsigned short* __restrict__ KpB,
                                               const float* __restrict__ Vp,
                                               unsigned short* __restrict__ Vpp) {
  int b = blockIdx.x >> 6, g = blockIdx.x & 63;
  int wv = threadIdx.x >> 6, lane = threadIdx.x & 63;
  int half = lane >> 5, l31 = lane & 31;
  const unsigned short* kb =
      KpB + ((size_t)(b * 4096 + g * 64 + l31)) * 16 + half * 8;
  bf8_t A0 = *reinterpret_cast<const bf8_t*>(kb);
  bf8_t A1 = *reinterpret_cast<const bf8_t*>(kb + 32 * 16);
  const unsigned short* qbase = Qp + ((size_t)b * 16384) * 16 + half * 8;
  fx16 z;
#pragma unroll
  for (int i = 0; i < 16; ++i) z[i] = 0.f;
  float l[32];
#pragma unroll
  for (int i = 0; i < 32; ++i) l[i] = 0.f;
  int t0 = wv * 32;                                // wave's first 32-k chunk
  bf8_t B = *reinterpret_cast<const bf8_t*>(qbase + (size_t)(t0 * 32 + l31) * 16);
  for (int i = 0; i < 32; ++i) {
    int tn = t0 + ((i + 1) & 31);
    bf8_t nB = *reinterpret_cast<const bf8_t*>(qbase + (size_t)(tn * 32 + l31) * 16);
    fx16 s0 = __builtin_amdgcn_mfma_f32_32x32x16_bf16(A0, B, z, 0, 0, 0);
    fx16 s1 = __builtin_amdgcn_mfma_f32_32x32x16_bf16(A1, B, z, 0, 0, 0);
#pragma unroll
    for (int r0 = 0; r0 < 16; ++r0) l[r0] += EXP2F(s0[r0]);
#pragma unroll
    for (int r0 = 0; r0 < 16; ++r0) l[16 + r0] += EXP2F(s1[r0]);
    B = nB;
  }
#pragma unroll
  for (int r0 = 0; r0 < 32; ++r0)
    for (int d = 1; d < 32; d <<= 1) l[r0] += __shfl_xor(l[r0], d);
  __shared__ float sl[16][2][32];
  __shared__ float Linv[64];
  __shared__ unsigned short Tv[32][72];            // [c][f-local], +8 pad
  if (l31 == 0) {
#pragma unroll
    for (int r0 = 0; r0 < 16; ++r0) {
      int row = (r0 & 3) + 8 * (r0 >> 2) + 4 * half;
      sl[wv][0][row] = l[r0];
      sl[wv][1][row] = l[16 + r0];
    }
  }
  __syncthreads();
  if (threadIdx.x < 64) {
    int fgi = threadIdx.x >> 5, row = threadIdx.x & 31;
    float L = 0.f;
#pragma unroll
    for (int w2 = 0; w2 < 16; ++w2) L += sl[w2][fgi][row];
    Linv[threadIdx.x] = 1.0f / L;
  }
  __syncthreads();
  if (threadIdx.x < 512) {                         // scale + pi-transpose
    int floc = threadIdx.x >> 3, c4 = (threadIdx.x & 7) * 4;
    float4 v = *reinterpret_cast<const float4*>(
        Vp + ((size_t)(b * 4096 + g * 64 + floc)) * 32 + c4);
    float s = Linv[floc];
    int dst = (floc & ~15) | pi16(floc & 15);
    Tv[c4][dst]     = f2bf(v.x * s);
    Tv[c4 + 1][dst] = f2bf(v.y * s);
    Tv[c4 + 2][dst] = f2bf(v.z * s);
    Tv[c4 + 3][dst] = f2bf(v.w * s);
  }
  __syncthreads();
  if (threadIdx.x < 256) {
    int c = threadIdx.x >> 3, u = threadIdx.x & 7;
    uint4 val = *reinterpret_cast<const uint4*>(&Tv[c][u * 8]);
    *reinterpret_cast<uint4*>(Vpp + ((size_t)(b * 32 + c)) * 4096 + g * 64 + u * 8) = val;
  }
}

// ------------------------- K3: attention + project --------------------------
// block = 512 thr (8 waves) per 64-k pair of tiles; waves split f 8-ways
// (16 chunks each), KB=2 per wave. Two-phase fp32 LDS reduction (32 KB),
// waves 0-3 do the (kt, ot) Wo epilogue.
__global__ void __launch_bounds__(512) k_attn(const unsigned short* __restrict__ Qp,
                                              const unsigned short* __restrict__ KpB,
                                              const unsigned short* __restrict__ Vpp,
                                              const unsigned short* __restrict__ Wop,
                                              const float* __restrict__ x,
                                              const float* __restrict__ gamma,
                                              float* __restrict__ out) {
  int b = blockIdx.x >> 8, kp = blockIdx.x & 255;
  int wv = threadIdx.x >> 6, lane = threadIdx.x & 63;
  int half = lane >> 5, l31 = lane & 31;
  int kbase = kp * 64;
  const unsigned short* qb = Qp + ((size_t)b * 16384 + kbase + l31) * 16 + half * 8;
  bf8_t Bq0 = *reinterpret_cast<const bf8_t*>(qb);
  bf8_t Bq1 = *reinterpret_cast<const bf8_t*>(qb + 32 * 16);
  fx16 z;
#pragma unroll
  for (int i = 0; i < 16; ++i) z[i] = 0.f;
  fx16 acc0 = z, acc1 = z;
  const unsigned short* kpB = KpB + ((size_t)b * 4096 + l31) * 16 + half * 8;
  const unsigned short* vpB = Vpp + ((size_t)(b * 32 + l31)) * 4096 + half * 8;
  int c0 = wv * 16;                                // wave's first f-chunk
  int f0 = c0 * 32;
  bf8_t Ak  = *reinterpret_cast<const bf8_t*>(kpB + (size_t)f0 * 16);
  bf8_t Av0 = *reinterpret_cast<const bf8_t*>(vpB + f0);
  bf8_t Av1 = *reinterpret_cast<const bf8_t*>(vpB + f0 + 16);
  for (int fc = 0; fc < 16; ++fc) {
    int f1 = (c0 + ((fc + 1) & 15)) * 32;          // wraps within wave's range
    bf8_t nAk  = *reinterpret_cast<const bf8_t*>(kpB + (size_t)f1 * 16);
    bf8_t nAv0 = *reinterpret_cast<const bf8_t*>(vpB + f1);
    bf8_t nAv1 = *reinterpret_cast<const bf8_t*>(vpB + f1 + 16);
    fx16 s0 = __builtin_amdgcn_mfma_f32_32x32x16_bf16(Ak, Bq0, z, 0, 0, 0);
    fx16 s1 = __builtin_amdgcn_mfma_f32_32x32x16_bf16(Ak, Bq1, z, 0, 0, 0);
    bf8_t P00, P01, P10, P11;
#pragma unroll
    for (int j = 0; j < 8; ++j) {
      P00[j] = (__bf16)EXP2F(s0[j]);
      P01[j] = (__bf16)EXP2F(s0[8 + j]);
    }
#pragma unroll
    for (int j = 0; j < 8; ++j) {
      P10[j] = (__bf16)EXP2F(s1[j]);
      P11[j] = (__bf16)EXP2F(s1[8 + j]);
    }
    acc0 = __builtin_amdgcn_mfma_f32_32x32x16_bf16(Av0, P00, acc0, 0, 0, 0);
    acc1 = __builtin_amdgcn_mfma_f32_32x32x16_bf16(Av0, P10, acc1, 0, 0, 0);
    acc0 = __builtin_amdgcn_mfma_f32_32x32x16_bf16(Av1, P01, acc0, 0, 0, 0);
    acc1 = __builtin_amdgcn_mfma_f32_32x32x16_bf16(Av1, P11, acc1, 0, 0, 0);
    Ak = nAk; Av0 = nAv0; Av1 = nAv1;
  }
  // two-phase reduction: waves 4-7 deposit, waves 0-3 merge pairwise, then
  // waves 0-3 sum the 4 pairwise slots.  [slot][kt][j4][lane][4] fp32, 32 KB.
  __shared__ float sacc[4][2][4][64][4];
  if (wv >= 4) {
    int s = wv - 4;
#pragma unroll
    for (int j4 = 0; j4 < 4; ++j4) {
      *reinterpret_cast<float4*>(&sacc[s][0][j4][lane][0]) =
          make_float4(acc0[4 * j4], acc0[4 * j4 + 1], acc0[4 * j4 + 2], acc0[4 * j4 + 3]);
      *reinterpret_cast<float4*>(&sacc[s][1][j4][lane][0]) =
          make_float4(acc1[4 * j4], acc1[4 * j4 + 1], acc1[4 * j4 + 2], acc1[4 * j4 + 3]);
    }
  }
  __syncthreads();
  if (wv < 4) {
#pragma unroll
    for (int j4 = 0; j4 < 4; ++j4) {
      float4 p0 = *reinterpret_cast<const float4*>(&sacc[wv][0][j4][lane][0]);
      float4 p1 = *reinterpret_cast<const float4*>(&sacc[wv][1][j4][lane][0]);
      p0.x += acc0[4 * j4]; p0.y += acc0[4 * j4 + 1];
      p0.z += acc0[4 * j4 + 2]; p0.w += acc0[4 * j4 + 3];
      p1.x += acc1[4 * j4]; p1.y += acc1[4 * j4 + 1];
      p1.z += acc1[4 * j4 + 2]; p1.w += acc1[4 * j4 + 3];
      *reinterpret_cast<float4*>(&sacc[wv][0][j4][lane][0]) = p0;
      *reinterpret_cast<float4*>(&sacc[wv][1][j4][lane][0]) = p1;
    }
  }
  __syncthreads();
  if (wv >= 4) return;
  int kt = wv & 1, ot = wv >> 1;
  fx16 tot;
#pragma unroll
  for (int j4 = 0; j4 < 4; ++j4) {
    float4 a0 = *reinterpret_cast<const float4*>(&sacc[0][kt][j4][lane][0]);
    float4 a1 = *reinterpret_cast<const float4*>(&sacc[1][kt][j4][lane][0]);
    float4 a2 = *reinterpret_cast<const float4*>(&sacc[2][kt][j4][lane][0]);
    float4 a3 = *reinterpret_cast<const float4*>(&sacc[3][kt][j4][lane][0]);
    tot[4 * j4]     = (a0.x + a1.x) + (a2.x + a3.x);
    tot[4 * j4 + 1] = (a0.y + a1.y) + (a2.y + a3.y);
    tot[4 * j4 + 2] = (a0.z + a1.z) + (a2.z + a3.z);
    tot[4 * j4 + 3] = (a0.w + a1.w) + (a2.w + a3.w);
  }
  bf8_t Ob0, Ob1;
#pragma unroll
  for (int j = 0; j < 8; ++j) { Ob0[j] = (__bf16)tot[j]; Ob1[j] = (__bf16)tot[8 + j]; }
  const unsigned short* wb = Wop + (ot * 32 + l31) * 32 + half * 8;
  bf8_t Aw0 = *reinterpret_cast<const bf8_t*>(wb);
  bf8_t Aw1 = *reinterpret_cast<const bf8_t*>(wb + 16);
  fx16 y = __builtin_amdgcn_mfma_f32_32x32x16_bf16(Aw0, Ob0, z, 0, 0, 0);
  y = __builtin_amdgcn_mfma_f32_32x32x16_bf16(Aw1, Ob1, y, 0, 0, 0);
  float g = gamma[0];
  int k = kbase + kt * 32 + l31;
  const float* xp = x + (size_t)b * 64 * 16384 + k;
  float* op = out + (size_t)b * 64 * 16384 + k;
#pragma unroll
  for (int r0 = 0; r0 < 16; ++r0) {
    int row = (r0 & 3) + 8 * (r0 >> 2) + 4 * half + ot * 32;
    op[(size_t)row * 16384] = fmaf(g, y[r0], xp[(size_t)row * 16384]);
  }
}

// ---------------------------------------------------------------------------
extern "C" void kernel_launch(void* const* d_in, const int* in_sizes, int n_in,
                              void* d_out, int out_size, void* d_ws, size_t ws_size,
                              hipStream_t stream) {
  const float* x     = (const float*)d_in[0];
  const float* Wq    = (const float*)d_in[1];
  const float* Wk    = (const float*)d_in[2];
  const float* Wv    = (const float*)d_in[3];
  const float* Wo    = (const float*)d_in[4];
  const float* gamma = (const float*)d_in[5];
  float* out = (float*)d_out;
  char* ws = (char*)d_ws;
  // workspace layout (bytes)
  unsigned short* Qp  = (unsigned short*)(ws + 0);        // 2 MB
  unsigned short* KpB = (unsigned short*)(ws + 2097152);  // 512 KB
  float*          Vp  = (float*)(ws + 2621440);           // 2 MB
  unsigned short* Vpp = (unsigned short*)(ws + 4718592);  // 1 MB
  unsigned short* Wop = (unsigned short*)(ws + 5767168);  // 4 KB

  k_qkv <<<dim3(257),  dim3(256),  0, stream>>>(x, Wq, Wk, Wv, Wo, Qp, KpB, Vp, Wop);
  k_lsum<<<dim3(256),  dim3(1024), 0, stream>>>(Qp, KpB, Vp, Vpp);
  k_attn<<<dim3(1024), dim3(512),  0, stream>>>(Qp, KpB, Vpp, Wop, x, gamma, out);
}